// Round 10
// baseline (339.864 us; speedup 1.0000x reference)
//
#include <hip/hip_runtime.h>
#include <hip/hip_bf16.h>

// MultiAgentGRULoop round 10: R6 structure + VALU/LDS diet.
//   - 256 blocks x 512 thr (8 waves), 1 block/CU, bounds(512,1). Unified
//     cell (R7/R8/R9 P/C + occupancy experiments all lost to this).
//   - bf16 inter-layer acts in d_ws (layers 0,1): epilogue's existing bf16
//     convert is reused; next layer stages with a pure short4->ds_write_b64
//     copy (NO converts). Same rounding as R6 -> identical numerics.
//   - s_act staging bf16 (b64) for l<2, f32 (b128) only for final layer.
//   - Hoisted per-layer global pointers; unroll-2 t-loop (static parity).
//   - One lgkmcnt-only barrier per cell; globals stay in flight (R6).
//   - Host falls back to all-f32-in-out variant if ws_size < 64 MB.

#define T_STEPS 64
#define HID 128
#define NL 3
#define RB 16
#define NTHR 512
#define NBLK 256
#define LSTR 136   // bf16 x/h row stride (shorts)
#define ASTR 132   // f32 act row stride (final layer)
#define BSTR 136   // bf16 act row stride (layers 0,1)

typedef __attribute__((ext_vector_type(8))) short bf16x8;
typedef __attribute__((ext_vector_type(4))) short short4v;
typedef __attribute__((ext_vector_type(4))) float f32x4;

static __device__ __forceinline__ short f2bf_s(float f) {
  __hip_bfloat16 b = __float2bfloat16(f);
  return __builtin_bit_cast(short, b);
}
__device__ __forceinline__ float sigm(float v) { return 1.f / (1.f + __expf(-v)); }
__device__ __forceinline__ float tanh_f(float v) { return 1.f - 2.f / (__expf(2.f * v) + 1.f); }

#define MFMA(A, B, C) __builtin_amdgcn_mfma_f32_16x16x32_bf16((A), (B), (C), 0, 0, 0)

template <bool USE_WS>
__global__ __launch_bounds__(NTHR, 1) void gru10(
    const float* __restrict__ x, const int* __restrict__ invalid,
    const float* __restrict__ w_ih, const float* __restrict__ w_hh,
    const float* __restrict__ b_ih, const float* __restrict__ b_hh,
    float* out, unsigned short* ws)
{
  __shared__ short s_x[2][RB * LSTR];     // input bf16 (x[t], x[t+1])
  __shared__ short s_h[2][RB * LSTR];     // h bf16 (masked), dbuf
  __shared__ float s_act[2][RB * ASTR];   // f32 act staging (final layer)
  __shared__ short s_actb[2][RB * BSTR];  // bf16 act staging (layers 0,1)
  __shared__ int   s_msk[T_STEPS * RB];   // mask, t-major

  const int tid = threadIdx.x;
  const int wave = tid >> 6, lane = tid & 63;
  const int lr = lane & 15, lq = lane >> 4;
  const int row_base = (int)blockIdx.x * RB;
  const int srow = tid >> 5, scol = (tid & 31) * 4;  // coalesced 4-elem map
  const int cb = wave * 16 + lq * 4;                 // epilogue col base

  for (int i = tid; i < T_STEPS * RB; i += NTHR) {
    const int t = i >> 4, r = i & 15;
    s_msk[i] = invalid[(size_t)(row_base + r) * T_STEPS + t];
  }

  for (int l = 0; l < NL; ++l) {
    const bool last = (l == NL - 1);
    // ---- per layer: weights -> bf16 register fragments ----
    bf16x8 wI[3][4], wH[3][4];
#pragma unroll
    for (int g = 0; g < 3; ++g)
#pragma unroll
      for (int kf = 0; kf < 4; ++kf) {
        const int wrow = g * HID + wave * 16 + lr;
        const int kofs = kf * 32 + lq * 8;
        const float* pI = w_ih + ((size_t)l * 3 * HID + wrow) * HID + kofs;
        const float* pH = w_hh + ((size_t)l * 3 * HID + wrow) * HID + kofs;
        float4 a = *(const float4*)pI, b = *(const float4*)(pI + 4);
        float vi[8] = {a.x, a.y, a.z, a.w, b.x, b.y, b.z, b.w};
        float4 c = *(const float4*)pH, d = *(const float4*)(pH + 4);
        float vh[8] = {c.x, c.y, c.z, c.w, d.x, d.y, d.z, d.w};
#pragma unroll
        for (int j = 0; j < 8; ++j) {
          wI[g][kf][j] = f2bf_s(vi[j]);
          wH[g][kf][j] = f2bf_s(vh[j]);
        }
      }
    float bRZ0[4], bRZ1[4], bNi[4], bNh[4];
#pragma unroll
    for (int ri = 0; ri < 4; ++ri) {
      const int c = cb + ri;
      const size_t base = (size_t)l * 3 * HID;
      bRZ0[ri] = b_ih[base + c] + b_hh[base + c];
      bRZ1[ri] = b_ih[base + HID + c] + b_hh[base + HID + c];
      bNi[ri]  = b_ih[base + 2 * HID + c];
      bNh[ri]  = b_hh[base + 2 * HID + c];
    }

    // ---- hoisted per-thread global pointers (staging map) ----
    const size_t soff = (size_t)(row_base + srow) * T_STEPS * HID + scol;
    const float* srcf = ((l == 0) ? x : (const float*)out) + soff;  // f32 source
    const unsigned short* srcb = ws + soff;                         // bf16 source
    float* outf = out + soff;
    unsigned short* wsf = ws + soff;
    const bool bf_src = USE_WS && (l > 0);
    const bool bf_dst = USE_WS && !last;

    // ---- h := 0, stage input[t=0] into buffer 0 ----
    for (int i = tid; i < RB * LSTR; i += NTHR) s_h[0][i] = 0;
    if (bf_src) {
      short4v c4 = *(const short4v*)srcb;
      *(short4v*)&s_x[0][srow * LSTR + scol] = c4;
    } else {
      float4 v = *(const float4*)srcf;
      short4v c4 = {f2bf_s(v.x), f2bf_s(v.y), f2bf_s(v.z), f2bf_s(v.w)};
      *(short4v*)&s_x[0][srow * LSTR + scol] = c4;
    }
    float hprev[4] = {0.f, 0.f, 0.f, 0.f};
    __syncthreads();

#pragma unroll 2
    for (int t = 0; t < T_STEPS; ++t) {
      const int p = t & 1;
      // ---- deferred store of act(t-1) (stays in flight across cells) ----
      if (t > 0) {
        if (bf_dst) {
          short4v a = *(const short4v*)&s_actb[p][srow * BSTR + scol];
          *(short4v*)(wsf + (size_t)(t - 1) * HID) = a;
        } else {
          float4 a = *(const float4*)&s_act[p][srow * ASTR + scol];
          *(float4*)(outf + (size_t)(t - 1) * HID) = a;
        }
      }
      // ---- prefetch next-step input + this-step mask ----
      float4 pinf;
      short4v pinb;
      if (t < T_STEPS - 1) {
        if (bf_src) pinb = *(const short4v*)(srcb + (size_t)(t + 1) * HID);
        else        pinf = *(const float4*)(srcf + (size_t)(t + 1) * HID);
      }
      const int mk = s_msk[t * RB + lr];

      // ---- MFMA phase, swapped operands: D[gate_col][act_row] ----
      f32x4 aI0 = {bRZ0[0], bRZ0[1], bRZ0[2], bRZ0[3]};
      f32x4 aH0 = (f32x4)(0.f);
      f32x4 aI1 = {bRZ1[0], bRZ1[1], bRZ1[2], bRZ1[3]};
      f32x4 aH1 = (f32x4)(0.f);
      f32x4 aN  = {bNi[0], bNi[1], bNi[2], bNi[3]};
      f32x4 aHn = {bNh[0], bNh[1], bNh[2], bNh[3]};
#pragma unroll
      for (int kf = 0; kf < 4; ++kf) {
        const int ao = lr * LSTR + kf * 32 + lq * 8;
        bf16x8 xh = *(const bf16x8*)&s_x[p][ao];
        bf16x8 hh = *(const bf16x8*)&s_h[p][ao];
        aI0 = MFMA(wI[0][kf], xh, aI0);
        aH0 = MFMA(wH[0][kf], hh, aH0);
        aI1 = MFMA(wI[1][kf], xh, aI1);
        aH1 = MFMA(wH[1][kf], hh, aH1);
        aN  = MFMA(wI[2][kf], xh, aN);
        aHn = MFMA(wH[2][kf], hh, aHn);
      }

      // ---- epilogue: lane owns act row lr, gate cols cb..cb+3 ----
      float4 actf;
      short4v ab, hb;
#pragma unroll
      for (int ri = 0; ri < 4; ++ri) {
        float rr = sigm(aI0[ri] + aH0[ri]);
        float zz = sigm(aI1[ri] + aH1[ri]);
        float nn = tanh_f(aN[ri] + rr * aHn[ri]);
        float hn = nn + zz * (hprev[ri] - nn);
        short hn_b = f2bf_s(hn);
        float hm = mk ? 0.f : hn;
        hprev[ri] = hm;
        ((float*)&actf)[ri] = last ? hm : hn;  // y masked; inter-layer unmasked
        ab[ri] = hn_b;                          // unmasked bf16 act
        hb[ri] = mk ? (short)0 : hn_b;          // masked bf16 h
      }
      *(short4v*)&s_h[p ^ 1][lr * LSTR + cb] = hb;
      if (bf_dst)
        *(short4v*)&s_actb[p ^ 1][lr * BSTR + cb] = ab;
      else
        *(float4*)&s_act[p ^ 1][lr * ASTR + cb] = actf;

      if (t < T_STEPS - 1) {
        if (bf_src) {
          *(short4v*)&s_x[p ^ 1][srow * LSTR + scol] = pinb;
        } else {
          short4v c4 = {f2bf_s(pinf.x), f2bf_s(pinf.y), f2bf_s(pinf.z), f2bf_s(pinf.w)};
          *(short4v*)&s_x[p ^ 1][srow * LSTR + scol] = c4;
        }
      }
      // ---- LDS-only sync; globals stay in flight ----
      asm volatile("s_waitcnt lgkmcnt(0)" ::: "memory");
      __builtin_amdgcn_s_barrier();
    }
    // ---- flush act(63) (lives in buffer 0) ----
    if (bf_dst) {
      short4v a = *(const short4v*)&s_actb[0][srow * BSTR + scol];
      *(short4v*)(wsf + (size_t)(T_STEPS - 1) * HID) = a;
    } else {
      float4 a = *(const float4*)&s_act[0][srow * ASTR + scol];
      *(float4*)(outf + (size_t)(T_STEPS - 1) * HID) = a;
    }
    __syncthreads();  // full drain: acts visible before next layer stages them
  }
}

extern "C" void kernel_launch(void* const* d_in, const int* in_sizes, int n_in,
                              void* d_out, int out_size, void* d_ws, size_t ws_size,
                              hipStream_t stream) {
  const float* x       = (const float*)d_in[0];
  const int*   invalid = (const int*)d_in[1];
  const float* w_ih    = (const float*)d_in[2];
  const float* w_hh    = (const float*)d_in[3];
  const float* b_ih    = (const float*)d_in[4];
  const float* b_hh    = (const float*)d_in[5];
  const size_t need = (size_t)4096 * T_STEPS * HID * sizeof(unsigned short);
  if (ws_size >= need) {
    gru10<true><<<dim3(NBLK), dim3(NTHR), 0, stream>>>(
        x, invalid, w_ih, w_hh, b_ih, b_hh, (float*)d_out, (unsigned short*)d_ws);
  } else {
    gru10<false><<<dim3(NBLK), dim3(NTHR), 0, stream>>>(
        x, invalid, w_ih, w_hh, b_ih, b_hh, (float*)d_out, (unsigned short*)d_ws);
  }
}